// Round 3
// baseline (2417.977 us; speedup 1.0000x reference)
//
#include <hip/hip_runtime.h>
#include <stdint.h>

// Problem constants
#define B_TOT   4096          // 4*1024 batch rows
#define D_IN    2048
#define D_OUT   2048
#define NCHUNK  4
#define LIN     512
#define LOUT    512
#define RK      8             // ring rank R
#define CORE_R_STRIDE 2097152 // LOUT*LIN*RK
#define CORE_O_STRIDE 4096    // LIN*RK

// Workspace layout (floats)
#define WS_XT    0                            // xT [2048][4096]           : 8388608
#define WS_GHAT  8388608                      // Ghat [4][8][512][8]       : 131072
#define WS_S     (8388608 + 131072)           // S    [4][4096][64]        : 1048576
#define WS_ENVT  (8388608 + 131072 + 1048576) // envT [4][64][4096]        : 1048576
#define WS_GSPL  10616832                     // split-G planes start (float index)
#define WS_BASE_BYTES 42467328ull             // 10616832 * 4
#define GSPL_CHUNK 16777216ull                // elems per chunk (= shorts per plane)
#define GSPL_CHUNK_BYTES 67108864ull          // hi+lo planes per chunk (2*CHUNK*2B)

typedef __attribute__((ext_vector_type(8))) __bf16 bf16x8;
typedef __attribute__((ext_vector_type(8))) unsigned short ushort8;
typedef __attribute__((ext_vector_type(4))) float f32x4;
typedef __attribute__((ext_vector_type(4))) unsigned int u32x4;

// ---------------- Kernel 1: transpose x [4096][2048] -> xT [2048][4096] --------
__global__ __launch_bounds__(256) void k_transpose(const float* __restrict__ x,
                                                   float* __restrict__ xT) {
    __shared__ float tile[32][33];
    int b0 = blockIdx.x * 32;
    int c0 = blockIdx.y * 32;
    int tx = threadIdx.x;      // 0..31
    int ty = threadIdx.y;      // 0..7
#pragma unroll
    for (int j = 0; j < 4; ++j)
        tile[ty + j * 8][tx] = x[(size_t)(b0 + ty + j * 8) * D_IN + c0 + tx];
    __syncthreads();
#pragma unroll
    for (int j = 0; j < 4; ++j)
        xT[(size_t)(c0 + ty + j * 8) * B_TOT + b0 + tx] = tile[tx][ty + j * 8];
}

// ---------------- Kernel 2: Ghat[i][r][xs] = sum_o G_i[r][o][xs] ---------------
__global__ __launch_bounds__(256) void k_reduce_g(const float* __restrict__ g0,
                                                  const float* __restrict__ g1,
                                                  const float* __restrict__ g2,
                                                  const float* __restrict__ g3,
                                                  float* __restrict__ ghat) {
    int i = blockIdx.z;
    int r = blockIdx.y;
    int xs = blockIdx.x * 256 + threadIdx.x;   // 0..4095
    const float* G = (i == 0) ? g0 : (i == 1) ? g1 : (i == 2) ? g2 : g3;
    const float* base = G + (size_t)r * CORE_R_STRIDE + xs;
    float acc = 0.f;
#pragma unroll 8
    for (int o = 0; o < LOUT; ++o) acc += base[(size_t)o * CORE_O_STRIDE];
    ghat[(size_t)i * 32768 + r * 4096 + xs] = acc;
}

// ---------------- Kernel 3: S[i][b][r*8+s] = sum_x Ghat[i][r][x][s]*x[b][i*512+x]
__global__ __launch_bounds__(256) void k_s(const float* __restrict__ x,
                                           const float* __restrict__ ghat,
                                           float* __restrict__ S) {
    int i = blockIdx.y;
    int tid = threadIdx.x;
    int rs = tid & 63;
    int b = blockIdx.x * 4 + (tid >> 6);
    int r = rs >> 3, s = rs & 7;
    const float* gh = ghat + (size_t)i * 32768 + r * 4096 + s;
    const float* xr = x + (size_t)b * D_IN + i * LIN;
    float acc = 0.f;
#pragma unroll 8
    for (int xi = 0; xi < LIN; ++xi) acc = fmaf(gh[xi * 8], xr[xi], acc);
    S[(size_t)i * (B_TOT * 64) + b * 64 + rs] = acc;
}

// ---------------- Kernel 4: chain products -> envT ----------------------------
__device__ __forceinline__ float mm8(float A, float B, int lane) {
    float c = 0.f;
#pragma unroll
    for (int p = 0; p < 8; ++p) {
        float a = __shfl(A, (lane & 56) | p, 64);
        float b = __shfl(B, (p << 3) | (lane & 7), 64);
        c = fmaf(a, b, c);
    }
    return c;
}
__device__ __forceinline__ float tr8(float E, int lane) {
    return __shfl(E, ((lane & 7) << 3) | (lane >> 3), 64);
}

__global__ __launch_bounds__(256) void k_env(const float* __restrict__ S,
                                             float* __restrict__ envT) {
    int tid = threadIdx.x;
    int lane = tid & 63;
    int b = blockIdx.x * 4 + (tid >> 6);
    float S0 = S[0 * (B_TOT * 64) + b * 64 + lane];
    float S1 = S[1 * (B_TOT * 64) + b * 64 + lane];
    float S2 = S[2 * (B_TOT * 64) + b * 64 + lane];
    float S3 = S[3 * (B_TOT * 64) + b * 64 + lane];

    float P1 = S0;
    float P2 = mm8(P1, S1, lane);
    float P3 = mm8(P2, S2, lane);
    float Q2 = S3;
    float Q1 = mm8(S2, Q2, lane);
    float Q0 = mm8(S1, Q1, lane);

    float e0 = tr8(Q0, lane);
    float e1 = tr8(mm8(Q1, P1, lane), lane);
    float e2 = tr8(mm8(Q2, P2, lane), lane);
    float e3 = tr8(P3, lane);

    envT[(size_t)(0 * 64 + lane) * B_TOT + b] = e0;
    envT[(size_t)(1 * 64 + lane) * B_TOT + b] = e1;
    envT[(size_t)(2 * 64 + lane) * B_TOT + b] = e2;
    envT[(size_t)(3 * 64 + lane) * B_TOT + b] = e3;
}

// ---------------- split helper via v_cvt_pk_bf16_f32 (6 VALU per pair) ---------
// hi = bf16_rne(v); lo = bf16_rne(v - float(hi))  (lo = v-hi is exact in f32;
// RNE hi keeps |lo| <= ulp/2 -> dropped Al*Bl term smaller than trunc scheme)
__device__ __forceinline__ uint2 split2pk(float a, float b) {
    unsigned int h, l;
    asm("v_cvt_pk_bf16_f32 %0, %1, %2" : "=v"(h) : "v"(a), "v"(b));
    float fa = __uint_as_float(h << 16);
    float fb = __uint_as_float(h & 0xffff0000u);
    float la = a - fa;
    float lb = b - fb;
    asm("v_cvt_pk_bf16_f32 %0, %1, %2" : "=v"(l) : "v"(la), "v"(lb));
    return make_uint2(h, l);
}

// ---------------- Kernel 4.5: precompute split-bf16 planes of G ----------------
// planes layout: [chunk][hi:CHUNK shorts][lo:CHUNK shorts], flat [r][o][k] order
// (same as G), so this is a linear pass. Grid = n_pre * 8192 blocks.
__global__ __launch_bounds__(256) void k_split_g(const float* __restrict__ g0,
                                                 const float* __restrict__ g1,
                                                 const float* __restrict__ g2,
                                                 const float* __restrict__ g3,
                                                 short* __restrict__ planes) {
    size_t e8 = ((size_t)blockIdx.x * 256 + threadIdx.x) * 8;  // 8 elems/thread
    int i = (int)(e8 >> 24);                                   // 2^24 elems/chunk
    const float* G = (i == 0) ? g0 : (i == 1) ? g1 : (i == 2) ? g2 : g3;
    size_t off = e8 & (GSPL_CHUNK - 1);
    float4 f0 = *(const float4*)(G + off);
    float4 f1 = *(const float4*)(G + off + 4);
    u32x4 H, L;
    uint2 p;
    p = split2pk(f0.x, f0.y); H.x = p.x; L.x = p.y;
    p = split2pk(f0.z, f0.w); H.y = p.x; L.y = p.y;
    p = split2pk(f1.x, f1.y); H.z = p.x; L.z = p.y;
    p = split2pk(f1.z, f1.w); H.w = p.x; L.w = p.y;
    short* hi = planes + (size_t)i * (2 * GSPL_CHUNK) + off;
    short* lo = hi + GSPL_CHUNK;
    *(u32x4*)hi = H;
    *(u32x4*)lo = L;
}

// ---------------- Kernel 5: pipelined MFMA GEMM, mixed pre-split/on-the-fly ----
// out_i = sum_r Z_{i,r} @ G_{i,r}^T, split-bf16 3-product emulation.
// BM=128 (b), BN=128 (o), BK=32 (k=(x,s)), 4 waves in 2x2 of 64x64.
// Chunks i < n_pre read precomputed bf16 hi/lo planes (zero split VALU in the
// K-loop); chunks >= n_pre split f32 G on the fly (r2-proven path, now with
// cvt_pk splits). Both paths: reg-staged double-buffered LDS, one barrier per
// K-step, loads for t+1 in flight across the MFMAs of t.
// LDS rows of 40 shorts (5 x 16B slots) -> uniform bank access on ds_read/write.
__global__ __launch_bounds__(256, 2) void k_gemm_mix(const float* __restrict__ g0,
                                                     const float* __restrict__ g1,
                                                     const float* __restrict__ g2,
                                                     const float* __restrict__ g3,
                                                     const short* __restrict__ planes,
                                                     int n_pre,
                                                     const float* __restrict__ xT,
                                                     const float* __restrict__ envT,
                                                     const float* __restrict__ bias,
                                                     float* __restrict__ out) {
    int l = blockIdx.x;                       // 0..511
    int c = (l & 7) | (((l >> 3) >> 5) << 3); // combo 0..15 (XCD swizzle)
    int b_idx = (l >> 3) & 31;                // b-tile 0..31
    int i = c >> 2;                           // chunk
    int o0 = (c & 3) * 128;
    int b0 = b_idx * 128;

    const float* xTi = xT + (size_t)i * LIN * B_TOT;
    const float* eTi = envT + (size_t)i * 64 * B_TOT;

    // rows of 40 shorts (5 x 16B slots, 4 used + 1 pad)
    __shared__ __align__(16) short Bhi[2][5120];
    __shared__ __align__(16) short Blo[2][5120];

    const int tid = threadIdx.x;
    const int lane = tid & 63;
    const int wave = tid >> 6;
    const int wm = (wave >> 1) * 64;
    const int wn = (wave & 1) * 64;
    const int l15 = lane & 15;
    const int quad = lane >> 4;

    // staging assignment: thread -> (row so, 16-elem half sh)
    const int so = tid >> 1;
    const int sh = (tid & 1) * 16;
    const int s0 = (tid & 1) * 2;        // first 16B slot this thread writes

    f32x4 acc[4][4];
#pragma unroll
    for (int mf = 0; mf < 4; ++mf)
#pragma unroll
        for (int nf = 0; nf < 4; ++nf) acc[mf][nf] = (f32x4){0.f, 0.f, 0.f, 0.f};

    // x register prefetch: xc[mf] = x[b = b0+wm+mf*16+l15][xrow = kk*4+quad]
    float xc[4], xn[4];
#pragma unroll
    for (int mf = 0; mf < 4; ++mf)
        xc[mf] = xTi[(size_t)quad * B_TOT + b0 + wm + mf * 16 + l15];

    if (i < n_pre) {
        // ================= PRE-SPLIT PATH =================
        const short* Phi = planes + (size_t)i * (2 * GSPL_CHUNK);
        const short* Plo = Phi + GSPL_CHUNK;
        const size_t soff0 = (size_t)(o0 + so) * CORE_O_STRIDE + sh;

        ushort8 h0, h1, l0, l1;          // staging registers
        auto LOADG = [&](int tn) {
            size_t off = soff0 + (size_t)(tn >> 7) * CORE_R_STRIDE + (size_t)(tn & 127) * 32;
            h0 = *(const ushort8*)(Phi + off);
            h1 = *(const ushort8*)(Phi + off + 8);
            l0 = *(const ushort8*)(Plo + off);
            l1 = *(const ushort8*)(Plo + off + 8);
        };
        auto STORE = [&](int pb) {
            *(ushort8*)&Bhi[pb][(so * 5 + s0) * 8]     = h0;
            *(ushort8*)&Bhi[pb][(so * 5 + s0 + 1) * 8] = h1;
            *(ushort8*)&Blo[pb][(so * 5 + s0) * 8]     = l0;
            *(ushort8*)&Blo[pb][(so * 5 + s0 + 1) * 8] = l1;
        };

        LOADG(0);
        STORE(0);
        __syncthreads();

        int t = 0;
        for (int r = 0; r < 8; ++r) {
            float e[4][8];
#pragma unroll
            for (int mf = 0; mf < 4; ++mf) {
                int m = b0 + wm + mf * 16 + l15;
#pragma unroll
                for (int s = 0; s < 8; ++s)
                    e[mf][s] = eTi[(size_t)(r * 8 + s) * B_TOT + m];
            }
            for (int kk = 0; kk < 128; ++kk, ++t) {
                const int p = t & 1;
                const bool more = (t + 1 < 1024);
                if (more) LOADG(t + 1);
#pragma unroll
                for (int mf = 0; mf < 4; ++mf)
                    xn[mf] = xTi[(size_t)(((kk + 1) & 127) * 4 + quad) * B_TOT
                                 + b0 + wm + mf * 16 + l15];

                bf16x8 bh[4], bl[4];
#pragma unroll
                for (int nf = 0; nf < 4; ++nf) {
                    int n = wn + nf * 16 + l15;
                    bh[nf] = *(const bf16x8*)&Bhi[p][(n * 5 + quad) * 8];
                    bl[nf] = *(const bf16x8*)&Blo[p][(n * 5 + quad) * 8];
                }

#pragma unroll
                for (int mf = 0; mf < 4; ++mf) {
                    float xv = xc[mf];
                    u32x4 AH, AL;
                    uint2 pr;
                    pr = split2pk(e[mf][0] * xv, e[mf][1] * xv); AH.x = pr.x; AL.x = pr.y;
                    pr = split2pk(e[mf][2] * xv, e[mf][3] * xv); AH.y = pr.x; AL.y = pr.y;
                    pr = split2pk(e[mf][4] * xv, e[mf][5] * xv); AH.z = pr.x; AL.z = pr.y;
                    pr = split2pk(e[mf][6] * xv, e[mf][7] * xv); AH.w = pr.x; AL.w = pr.y;
                    bf16x8 Ah = __builtin_bit_cast(bf16x8, AH);
                    bf16x8 Al = __builtin_bit_cast(bf16x8, AL);
#pragma unroll
                    for (int nf = 0; nf < 4; ++nf) {
                        acc[mf][nf] = __builtin_amdgcn_mfma_f32_16x16x32_bf16(Ah, bh[nf], acc[mf][nf], 0, 0, 0);
                        acc[mf][nf] = __builtin_amdgcn_mfma_f32_16x16x32_bf16(Ah, bl[nf], acc[mf][nf], 0, 0, 0);
                        acc[mf][nf] = __builtin_amdgcn_mfma_f32_16x16x32_bf16(Al, bh[nf], acc[mf][nf], 0, 0, 0);
                    }
                }

                if (more) STORE(p ^ 1);
                __syncthreads();
#pragma unroll
                for (int mf = 0; mf < 4; ++mf) xc[mf] = xn[mf];
            }
        }
    } else {
        // ================= ON-THE-FLY PATH =================
        const float* G = (i == 0) ? g0 : (i == 1) ? g1 : (i == 2) ? g2 : g3;
        const float* gsrc = G + (size_t)(o0 + so) * CORE_O_STRIDE + sh;

        float4 f0, f1, f2, f3;           // staging registers
        auto LOADG = [&](int tn) {
            const float* p = gsrc + (size_t)(tn >> 7) * CORE_R_STRIDE + (tn & 127) * 32;
            f0 = *(const float4*)(p);
            f1 = *(const float4*)(p + 4);
            f2 = *(const float4*)(p + 8);
            f3 = *(const float4*)(p + 12);
        };
        auto STORE = [&](int pb) {
            u32x4 H0, L0, H1, L1;
            uint2 q;
            q = split2pk(f0.x, f0.y); H0.x = q.x; L0.x = q.y;
            q = split2pk(f0.z, f0.w); H0.y = q.x; L0.y = q.y;
            q = split2pk(f1.x, f1.y); H0.z = q.x; L0.z = q.y;
            q = split2pk(f1.z, f1.w); H0.w = q.x; L0.w = q.y;
            q = split2pk(f2.x, f2.y); H1.x = q.x; L1.x = q.y;
            q = split2pk(f2.z, f2.w); H1.y = q.x; L1.y = q.y;
            q = split2pk(f3.x, f3.y); H1.z = q.x; L1.z = q.y;
            q = split2pk(f3.z, f3.w); H1.w = q.x; L1.w = q.y;
            *(u32x4*)&Bhi[pb][(so * 5 + s0) * 8]     = H0;
            *(u32x4*)&Bhi[pb][(so * 5 + s0 + 1) * 8] = H1;
            *(u32x4*)&Blo[pb][(so * 5 + s0) * 8]     = L0;
            *(u32x4*)&Blo[pb][(so * 5 + s0 + 1) * 8] = L1;
        };

        LOADG(0);
        STORE(0);
        __syncthreads();

        int t = 0;
        for (int r = 0; r < 8; ++r) {
            float e[4][8];
#pragma unroll
            for (int mf = 0; mf < 4; ++mf) {
                int m = b0 + wm + mf * 16 + l15;
#pragma unroll
                for (int s = 0; s < 8; ++s)
                    e[mf][s] = eTi[(size_t)(r * 8 + s) * B_TOT + m];
            }
            for (int kk = 0; kk < 128; ++kk, ++t) {
                const int p = t & 1;
                const bool more = (t + 1 < 1024);
                if (more) LOADG(t + 1);
#pragma unroll
                for (int mf = 0; mf < 4; ++mf)
                    xn[mf] = xTi[(size_t)(((kk + 1) & 127) * 4 + quad) * B_TOT
                                 + b0 + wm + mf * 16 + l15];

                bf16x8 bh[4], bl[4];
#pragma unroll
                for (int nf = 0; nf < 4; ++nf) {
                    int n = wn + nf * 16 + l15;
                    bh[nf] = *(const bf16x8*)&Bhi[p][(n * 5 + quad) * 8];
                    bl[nf] = *(const bf16x8*)&Blo[p][(n * 5 + quad) * 8];
                }

#pragma unroll
                for (int mf = 0; mf < 4; ++mf) {
                    float xv = xc[mf];
                    u32x4 AH, AL;
                    uint2 pr;
                    pr = split2pk(e[mf][0] * xv, e[mf][1] * xv); AH.x = pr.x; AL.x = pr.y;
                    pr = split2pk(e[mf][2] * xv, e[mf][3] * xv); AH.y = pr.x; AL.y = pr.y;
                    pr = split2pk(e[mf][4] * xv, e[mf][5] * xv); AH.z = pr.x; AL.z = pr.y;
                    pr = split2pk(e[mf][6] * xv, e[mf][7] * xv); AH.w = pr.x; AL.w = pr.y;
                    bf16x8 Ah = __builtin_bit_cast(bf16x8, AH);
                    bf16x8 Al = __builtin_bit_cast(bf16x8, AL);
#pragma unroll
                    for (int nf = 0; nf < 4; ++nf) {
                        acc[mf][nf] = __builtin_amdgcn_mfma_f32_16x16x32_bf16(Ah, bh[nf], acc[mf][nf], 0, 0, 0);
                        acc[mf][nf] = __builtin_amdgcn_mfma_f32_16x16x32_bf16(Ah, bl[nf], acc[mf][nf], 0, 0, 0);
                        acc[mf][nf] = __builtin_amdgcn_mfma_f32_16x16x32_bf16(Al, bh[nf], acc[mf][nf], 0, 0, 0);
                    }
                }

                if (more) STORE(p ^ 1);
                __syncthreads();
#pragma unroll
                for (int mf = 0; mf < 4; ++mf) xc[mf] = xn[mf];
            }
        }
    }

    // ---- epilogue: C/D layout col=lane&15, row=quad*4+reg ----
#pragma unroll
    for (int nf = 0; nf < 4; ++nf) {
        int col = o0 + wn + nf * 16 + l15;
        float bv = bias[i * LOUT + col];
#pragma unroll
        for (int mf = 0; mf < 4; ++mf) {
#pragma unroll
            for (int reg = 0; reg < 4; ++reg) {
                int row = b0 + wm + mf * 16 + quad * 4 + reg;
                out[(size_t)row * D_OUT + i * LOUT + col] = acc[mf][nf][reg] + bv;
            }
        }
    }
}

extern "C" void kernel_launch(void* const* d_in, const int* in_sizes, int n_in,
                              void* d_out, int out_size, void* d_ws, size_t ws_size,
                              hipStream_t stream) {
    const float* x    = (const float*)d_in[0];
    const float* g0   = (const float*)d_in[1];
    const float* g1   = (const float*)d_in[2];
    const float* g2   = (const float*)d_in[3];
    const float* g3   = (const float*)d_in[4];
    const float* bias = (const float*)d_in[5];
    float* out = (float*)d_out;
    float* ws = (float*)d_ws;

    float* xT   = ws + WS_XT;
    float* ghat = ws + WS_GHAT;
    float* S    = ws + WS_S;
    float* envT = ws + WS_ENVT;
    short* planes = (short*)(ws + WS_GSPL);

    int n_pre = 0;
    if (ws_size > WS_BASE_BYTES)
        n_pre = (int)((ws_size - WS_BASE_BYTES) / GSPL_CHUNK_BYTES);
    if (n_pre > 4) n_pre = 4;

    k_transpose<<<dim3(128, 64), dim3(32, 8), 0, stream>>>(x, xT);
    k_reduce_g<<<dim3(16, 8, 4), 256, 0, stream>>>(g0, g1, g2, g3, ghat);
    k_s<<<dim3(1024, 4), 256, 0, stream>>>(x, ghat, S);
    k_env<<<1024, 256, 0, stream>>>(S, envT);
    if (n_pre > 0)
        k_split_g<<<n_pre * 8192, 256, 0, stream>>>(g0, g1, g2, g3, planes);
    k_gemm_mix<<<512, 256, 0, stream>>>(g0, g1, g2, g3, planes, n_pre,
                                        xT, envT, bias, out);
}

// Round 4
// 2121.598 us; speedup vs baseline: 1.1397x; 1.1397x over previous
//
#include <hip/hip_runtime.h>
#include <stdint.h>

// Problem constants
#define B_TOT   4096          // 4*1024 batch rows
#define D_IN    2048
#define D_OUT   2048
#define NCHUNK  4
#define LIN     512
#define LOUT    512
#define RK      8             // ring rank R
#define CORE_R_STRIDE 2097152 // LOUT*LIN*RK
#define CORE_O_STRIDE 4096    // LIN*RK

// Workspace layout (floats)
#define WS_XT    0                            // xT [2048][4096]           : 8388608
#define WS_GHAT  8388608                      // Ghat [4][8][512][8]       : 131072
#define WS_S     (8388608 + 131072)           // S    [4][4096][64]        : 1048576
#define WS_ENVT  (8388608 + 131072 + 1048576) // envT [4][64][4096]        : 1048576

typedef __attribute__((ext_vector_type(8))) __bf16 bf16x8;
typedef __attribute__((ext_vector_type(4))) float f32x4;
typedef __attribute__((ext_vector_type(4))) unsigned int u32x4;

// ---------------- Kernel 1: transpose x [4096][2048] -> xT [2048][4096] --------
__global__ __launch_bounds__(256) void k_transpose(const float* __restrict__ x,
                                                   float* __restrict__ xT) {
    __shared__ float tile[32][33];
    int b0 = blockIdx.x * 32;
    int c0 = blockIdx.y * 32;
    int tx = threadIdx.x;      // 0..31
    int ty = threadIdx.y;      // 0..7
#pragma unroll
    for (int j = 0; j < 4; ++j)
        tile[ty + j * 8][tx] = x[(size_t)(b0 + ty + j * 8) * D_IN + c0 + tx];
    __syncthreads();
#pragma unroll
    for (int j = 0; j < 4; ++j)
        xT[(size_t)(c0 + ty + j * 8) * B_TOT + b0 + tx] = tile[tx][ty + j * 8];
}

// ---------------- Kernel 2: Ghat[i][r][xs] = sum_o G_i[r][o][xs] ---------------
__global__ __launch_bounds__(256) void k_reduce_g(const float* __restrict__ g0,
                                                  const float* __restrict__ g1,
                                                  const float* __restrict__ g2,
                                                  const float* __restrict__ g3,
                                                  float* __restrict__ ghat) {
    int i = blockIdx.z;
    int r = blockIdx.y;
    int xs = blockIdx.x * 256 + threadIdx.x;   // 0..4095
    const float* G = (i == 0) ? g0 : (i == 1) ? g1 : (i == 2) ? g2 : g3;
    const float* base = G + (size_t)r * CORE_R_STRIDE + xs;
    float acc = 0.f;
#pragma unroll 8
    for (int o = 0; o < LOUT; ++o) acc += base[(size_t)o * CORE_O_STRIDE];
    ghat[(size_t)i * 32768 + r * 4096 + xs] = acc;
}

// ---------------- Kernel 3: S[i][b][r*8+s] = sum_x Ghat[i][r][x][s]*x[b][i*512+x]
__global__ __launch_bounds__(256) void k_s(const float* __restrict__ x,
                                           const float* __restrict__ ghat,
                                           float* __restrict__ S) {
    int i = blockIdx.y;
    int tid = threadIdx.x;
    int rs = tid & 63;
    int b = blockIdx.x * 4 + (tid >> 6);
    int r = rs >> 3, s = rs & 7;
    const float* gh = ghat + (size_t)i * 32768 + r * 4096 + s;
    const float* xr = x + (size_t)b * D_IN + i * LIN;
    float acc = 0.f;
#pragma unroll 8
    for (int xi = 0; xi < LIN; ++xi) acc = fmaf(gh[xi * 8], xr[xi], acc);
    S[(size_t)i * (B_TOT * 64) + b * 64 + rs] = acc;
}

// ---------------- Kernel 4: chain products -> envT ----------------------------
__device__ __forceinline__ float mm8(float A, float B, int lane) {
    float c = 0.f;
#pragma unroll
    for (int p = 0; p < 8; ++p) {
        float a = __shfl(A, (lane & 56) | p, 64);
        float b = __shfl(B, (p << 3) | (lane & 7), 64);
        c = fmaf(a, b, c);
    }
    return c;
}
__device__ __forceinline__ float tr8(float E, int lane) {
    return __shfl(E, ((lane & 7) << 3) | (lane >> 3), 64);
}

__global__ __launch_bounds__(256) void k_env(const float* __restrict__ S,
                                             float* __restrict__ envT) {
    int tid = threadIdx.x;
    int lane = tid & 63;
    int b = blockIdx.x * 4 + (tid >> 6);
    float S0 = S[0 * (B_TOT * 64) + b * 64 + lane];
    float S1 = S[1 * (B_TOT * 64) + b * 64 + lane];
    float S2 = S[2 * (B_TOT * 64) + b * 64 + lane];
    float S3 = S[3 * (B_TOT * 64) + b * 64 + lane];

    float P1 = S0;
    float P2 = mm8(P1, S1, lane);
    float P3 = mm8(P2, S2, lane);
    float Q2 = S3;
    float Q1 = mm8(S2, Q2, lane);
    float Q0 = mm8(S1, Q1, lane);

    float e0 = tr8(Q0, lane);
    float e1 = tr8(mm8(Q1, P1, lane), lane);
    float e2 = tr8(mm8(Q2, P2, lane), lane);
    float e3 = tr8(P3, lane);

    envT[(size_t)(0 * 64 + lane) * B_TOT + b] = e0;
    envT[(size_t)(1 * 64 + lane) * B_TOT + b] = e1;
    envT[(size_t)(2 * 64 + lane) * B_TOT + b] = e2;
    envT[(size_t)(3 * 64 + lane) * B_TOT + b] = e3;
}

// ---------------- split helper via v_cvt_pk_bf16_f32 (6 VALU per pair) ---------
// hi = bf16_rne(v); lo = bf16_rne(v - float(hi))
__device__ __forceinline__ uint2 split2pk(float a, float b) {
    unsigned int h, l;
    asm("v_cvt_pk_bf16_f32 %0, %1, %2" : "=v"(h) : "v"(a), "v"(b));
    float fa = __uint_as_float(h << 16);
    float fb = __uint_as_float(h & 0xffff0000u);
    float la = a - fa;
    float lb = b - fb;
    asm("v_cvt_pk_bf16_f32 %0, %1, %2" : "=v"(l) : "v"(la), "v"(lb));
    return make_uint2(h, l);
}

// ---------------- Kernel 5: 2-deep pipelined MFMA GEMM ------------------------
// out_i = sum_r Z_{i,r} @ G_{i,r}^T, split-bf16 3-product emulation.
// BM=128 (b), BN=128 (o), BK=32 (k=(x,s)), 4 waves in 2x2 of 64x64.
//
// 2-deep register pipeline (removes the per-step vmcnt stall of r2/r3):
//   named register sets A/B (static indexing), K-loop unrolled by 2.
//   even step t: issue LOADGA(t+2); compute buf0; STOREB (tile t+1, loaded a
//                full iteration ago -> vmcnt satisfied) -> buf1; barrier.
//   odd  step:   issue LOADGB(t+3); compute buf1; STOREA (tile t+2) -> buf0.
//
// LDS rows of 40 shorts (5 x 16B slots) -> uniform bank access on ds_read/write.
// A (=env*x) generated in registers via cvt_pk splits; x register-prefetched.
__global__ __launch_bounds__(256, 2) void k_gemm_pipe2(const float* __restrict__ g0,
                                                       const float* __restrict__ g1,
                                                       const float* __restrict__ g2,
                                                       const float* __restrict__ g3,
                                                       const float* __restrict__ xT,
                                                       const float* __restrict__ envT,
                                                       const float* __restrict__ bias,
                                                       float* __restrict__ out) {
    int l = blockIdx.x;                       // 0..511
    int c = (l & 7) | (((l >> 3) >> 5) << 3); // combo 0..15 (XCD swizzle)
    int b_idx = (l >> 3) & 31;                // b-tile 0..31
    int i = c >> 2;                           // chunk
    int o0 = (c & 3) * 128;
    int b0 = b_idx * 128;

    const float* G = (i == 0) ? g0 : (i == 1) ? g1 : (i == 2) ? g2 : g3;
    const float* xTi = xT + (size_t)i * LIN * B_TOT;
    const float* eTi = envT + (size_t)i * 64 * B_TOT;

    // rows of 40 shorts (5 x 16B slots, 4 used + 1 pad)
    __shared__ __align__(16) short Bhi[2][5120];
    __shared__ __align__(16) short Blo[2][5120];

    const int tid = threadIdx.x;
    const int lane = tid & 63;
    const int wave = tid >> 6;
    const int wm = (wave >> 1) * 64;
    const int wn = (wave & 1) * 64;
    const int l15 = lane & 15;
    const int quad = lane >> 4;

    // staging assignment: thread -> (row so, 16-float half sh)
    const int so = tid >> 1;
    const int sh = (tid & 1) * 16;
    const int s0 = (tid & 1) * 2;        // first 16B slot this thread writes
    const float* gsrc = G + (size_t)(o0 + so) * CORE_O_STRIDE + sh;

    f32x4 acc[4][4];
#pragma unroll
    for (int mf = 0; mf < 4; ++mf)
#pragma unroll
        for (int nf = 0; nf < 4; ++nf) acc[mf][nf] = (f32x4){0.f, 0.f, 0.f, 0.f};

    // two named staging register sets (2-deep pipeline)
    float4 fA0, fA1, fA2, fA3;
    float4 fB0, fB1, fB2, fB3;

    auto LOADGA = [&](int tn) {
        const float* p = gsrc + (size_t)(tn >> 7) * CORE_R_STRIDE + (tn & 127) * 32;
        fA0 = *(const float4*)(p);
        fA1 = *(const float4*)(p + 4);
        fA2 = *(const float4*)(p + 8);
        fA3 = *(const float4*)(p + 12);
    };
    auto LOADGB = [&](int tn) {
        const float* p = gsrc + (size_t)(tn >> 7) * CORE_R_STRIDE + (tn & 127) * 32;
        fB0 = *(const float4*)(p);
        fB1 = *(const float4*)(p + 4);
        fB2 = *(const float4*)(p + 8);
        fB3 = *(const float4*)(p + 12);
    };
    auto STOREA = [&](int pb) {
        u32x4 H0, L0, H1, L1;
        uint2 q;
        q = split2pk(fA0.x, fA0.y); H0.x = q.x; L0.x = q.y;
        q = split2pk(fA0.z, fA0.w); H0.y = q.x; L0.y = q.y;
        q = split2pk(fA1.x, fA1.y); H0.z = q.x; L0.z = q.y;
        q = split2pk(fA1.z, fA1.w); H0.w = q.x; L0.w = q.y;
        q = split2pk(fA2.x, fA2.y); H1.x = q.x; L1.x = q.y;
        q = split2pk(fA2.z, fA2.w); H1.y = q.x; L1.y = q.y;
        q = split2pk(fA3.x, fA3.y); H1.z = q.x; L1.z = q.y;
        q = split2pk(fA3.z, fA3.w); H1.w = q.x; L1.w = q.y;
        *(u32x4*)&Bhi[pb][(so * 5 + s0) * 8]     = H0;
        *(u32x4*)&Bhi[pb][(so * 5 + s0 + 1) * 8] = H1;
        *(u32x4*)&Blo[pb][(so * 5 + s0) * 8]     = L0;
        *(u32x4*)&Blo[pb][(so * 5 + s0 + 1) * 8] = L1;
    };
    auto STOREB = [&](int pb) {
        u32x4 H0, L0, H1, L1;
        uint2 q;
        q = split2pk(fB0.x, fB0.y); H0.x = q.x; L0.x = q.y;
        q = split2pk(fB0.z, fB0.w); H0.y = q.x; L0.y = q.y;
        q = split2pk(fB1.x, fB1.y); H0.z = q.x; L0.z = q.y;
        q = split2pk(fB1.z, fB1.w); H0.w = q.x; L0.w = q.y;
        q = split2pk(fB2.x, fB2.y); H1.x = q.x; L1.x = q.y;
        q = split2pk(fB2.z, fB2.w); H1.y = q.x; L1.y = q.y;
        q = split2pk(fB3.x, fB3.y); H1.z = q.x; L1.z = q.y;
        q = split2pk(fB3.z, fB3.w); H1.w = q.x; L1.w = q.y;
        *(u32x4*)&Bhi[pb][(so * 5 + s0) * 8]     = H0;
        *(u32x4*)&Bhi[pb][(so * 5 + s0 + 1) * 8] = H1;
        *(u32x4*)&Blo[pb][(so * 5 + s0) * 8]     = L0;
        *(u32x4*)&Blo[pb][(so * 5 + s0 + 1) * 8] = L1;
    };

    // x register prefetch: xc[mf] = x[b = b0+wm+mf*16+l15][xrow = kk*4+quad]
    float xc[4];
#pragma unroll
    for (int mf = 0; mf < 4; ++mf)
        xc[mf] = xTi[(size_t)quad * B_TOT + b0 + wm + mf * 16 + l15];

    float e[4][8];

    // compute one K-step from buf p; also prefetch x for step kk+1
    auto COMP = [&](int p, int kk) {
        float xn[4];
#pragma unroll
        for (int mf = 0; mf < 4; ++mf)
            xn[mf] = xTi[(size_t)(((kk + 1) & 127) * 4 + quad) * B_TOT
                         + b0 + wm + mf * 16 + l15];

        bf16x8 bh[4], bl[4];
#pragma unroll
        for (int nf = 0; nf < 4; ++nf) {
            int n = wn + nf * 16 + l15;
            bh[nf] = *(const bf16x8*)&Bhi[p][(n * 5 + quad) * 8];
            bl[nf] = *(const bf16x8*)&Blo[p][(n * 5 + quad) * 8];
        }

        __builtin_amdgcn_s_setprio(1);
#pragma unroll
        for (int mf = 0; mf < 4; ++mf) {
            float xv = xc[mf];
            u32x4 AH, AL;
            uint2 pr;
            pr = split2pk(e[mf][0] * xv, e[mf][1] * xv); AH.x = pr.x; AL.x = pr.y;
            pr = split2pk(e[mf][2] * xv, e[mf][3] * xv); AH.y = pr.x; AL.y = pr.y;
            pr = split2pk(e[mf][4] * xv, e[mf][5] * xv); AH.z = pr.x; AL.z = pr.y;
            pr = split2pk(e[mf][6] * xv, e[mf][7] * xv); AH.w = pr.x; AL.w = pr.y;
            bf16x8 Ah = __builtin_bit_cast(bf16x8, AH);
            bf16x8 Al = __builtin_bit_cast(bf16x8, AL);
#pragma unroll
            for (int nf = 0; nf < 4; ++nf) {
                acc[mf][nf] = __builtin_amdgcn_mfma_f32_16x16x32_bf16(Ah, bh[nf], acc[mf][nf], 0, 0, 0);
                acc[mf][nf] = __builtin_amdgcn_mfma_f32_16x16x32_bf16(Ah, bl[nf], acc[mf][nf], 0, 0, 0);
                acc[mf][nf] = __builtin_amdgcn_mfma_f32_16x16x32_bf16(Al, bh[nf], acc[mf][nf], 0, 0, 0);
            }
        }
        __builtin_amdgcn_s_setprio(0);
#pragma unroll
        for (int mf = 0; mf < 4; ++mf) xc[mf] = xn[mf];
    };

    // prologue: fill 2-deep pipe, stage tile 0 into buf 0
    LOADGA(0);
    LOADGB(1);
    STOREA(0);
    __syncthreads();

    int t = 0;
    for (int r = 0; r < 8; ++r) {
        // env for this r: e[mf][s], held in registers for 128 K-steps
#pragma unroll
        for (int mf = 0; mf < 4; ++mf) {
            int m = b0 + wm + mf * 16 + l15;
#pragma unroll
            for (int s = 0; s < 8; ++s)
                e[mf][s] = eTi[(size_t)(r * 8 + s) * B_TOT + m];
        }
        for (int kk = 0; kk < 128; kk += 2, t += 2) {
            // ---- even step t: compute buf0, store tile t+1 -> buf1 ----
            if (t + 2 < 1024) LOADGA(t + 2);
            COMP(0, kk);
            STOREB(1);                       // regs loaded a full iter ago
            __syncthreads();
            // ---- odd step t+1: compute buf1, store tile t+2 -> buf0 ----
            if (t + 3 < 1024) LOADGB(t + 3);
            COMP(1, kk + 1);
            if (t + 2 < 1024) STOREA(0);
            __syncthreads();
        }
    }

    // ---- epilogue: C/D layout col=lane&15, row=quad*4+reg ----
#pragma unroll
    for (int nf = 0; nf < 4; ++nf) {
        int col = o0 + wn + nf * 16 + l15;
        float bv = bias[i * LOUT + col];
#pragma unroll
        for (int mf = 0; mf < 4; ++mf) {
#pragma unroll
            for (int reg = 0; reg < 4; ++reg) {
                int row = b0 + wm + mf * 16 + quad * 4 + reg;
                out[(size_t)row * D_OUT + i * LOUT + col] = acc[mf][nf][reg] + bv;
            }
        }
    }
}

extern "C" void kernel_launch(void* const* d_in, const int* in_sizes, int n_in,
                              void* d_out, int out_size, void* d_ws, size_t ws_size,
                              hipStream_t stream) {
    const float* x    = (const float*)d_in[0];
    const float* g0   = (const float*)d_in[1];
    const float* g1   = (const float*)d_in[2];
    const float* g2   = (const float*)d_in[3];
    const float* g3   = (const float*)d_in[4];
    const float* bias = (const float*)d_in[5];
    float* out = (float*)d_out;
    float* ws = (float*)d_ws;

    float* xT   = ws + WS_XT;
    float* ghat = ws + WS_GHAT;
    float* S    = ws + WS_S;
    float* envT = ws + WS_ENVT;

    k_transpose<<<dim3(128, 64), dim3(32, 8), 0, stream>>>(x, xT);
    k_reduce_g<<<dim3(16, 8, 4), 256, 0, stream>>>(g0, g1, g2, g3, ghat);
    k_s<<<dim3(1024, 4), 256, 0, stream>>>(x, ghat, S);
    k_env<<<1024, 256, 0, stream>>>(S, envT);
    k_gemm_pipe2<<<512, 256, 0, stream>>>(g0, g1, g2, g3, xT, envT, bias, out);
}